// Round 7
// baseline (88.290 us; speedup 1.0000x reference)
//
#include <hip/hip_runtime.h>
#include <hip/hip_bf16.h>

#define DEVI __device__ __forceinline__

typedef __attribute__((ext_vector_type(4))) float f32x4;
typedef __attribute__((ext_vector_type(8))) short bf16x8;

static constexpr int BB  = 8;     // batch
static constexpr int SEQ = 1024;  // sequence length
static constexpr int DIM = 512;   // model dim = H*DQ
static constexpr int NH  = 8;     // heads
static constexpr int HD  = 64;    // head dim
static constexpr int M   = BB * SEQ;  // 8192 flattened rows

// ---------- helpers ----------

DEVI unsigned short f2bf(float x) {
  unsigned int u = __builtin_bit_cast(unsigned int, x);
  u += 0x7fffu + ((u >> 16) & 1u);
  return (unsigned short)(u >> 16);
}

DEVI float fexp2(float x) {
#if __has_builtin(__builtin_amdgcn_exp2f)
  return __builtin_amdgcn_exp2f(x);
#else
  float r; asm("v_exp_f32 %0, %1" : "=v"(r) : "v"(x)); return r;
#endif
}

DEVI void gload_lds16(const unsigned short* g, unsigned short* l) {
  __builtin_amdgcn_global_load_lds(
      (const __attribute__((address_space(1))) void*)g,
      (__attribute__((address_space(3))) void*)l, 16, 0, 0);
}

DEVI bf16x8 cvt8(float4 a, float4 b) {
  bf16x8 r;
  r[0] = (short)f2bf(a.x); r[1] = (short)f2bf(a.y);
  r[2] = (short)f2bf(a.z); r[3] = (short)f2bf(a.w);
  r[4] = (short)f2bf(b.x); r[5] = (short)f2bf(b.y);
  r[6] = (short)f2bf(b.z); r[7] = (short)f2bf(b.w);
  return r;
}

// ---------- fp32 (K x N) -> bf16 transposed (N x K), 4 weights in one launch ----------

__global__ __launch_bounds__(256) void cvt_t4_kernel(const float* __restrict__ w0,
                                                     const float* __restrict__ w1,
                                                     const float* __restrict__ w2,
                                                     const float* __restrict__ w3,
                                                     unsigned short* __restrict__ o0,
                                                     unsigned short* __restrict__ o1,
                                                     unsigned short* __restrict__ o2,
                                                     unsigned short* __restrict__ o3) {
  const float* in = (blockIdx.z == 0) ? w0 : ((blockIdx.z == 1) ? w1 : ((blockIdx.z == 2) ? w2 : w3));
  unsigned short* out = (blockIdx.z == 0) ? o0 : ((blockIdx.z == 1) ? o1 : ((blockIdx.z == 2) ? o2 : o3));
  __shared__ float tile[32][33];
  int n0 = blockIdx.x * 32, k0 = blockIdx.y * 32;
  int tx = threadIdx.x & 31, ty = threadIdx.x >> 5;  // 32 x 8
#pragma unroll
  for (int r = 0; r < 32; r += 8)
    tile[ty + r][tx] = in[(size_t)(k0 + ty + r) * DIM + n0 + tx];
  __syncthreads();
#pragma unroll
  for (int r = 0; r < 32; r += 8)
    out[(size_t)(n0 + ty + r) * DIM + k0 + tx] = f2bf(tile[tx][ty + r]);
}

// ---------- fused projection GEMM ----------
// A: fp32 (M x 512) read directly (convert fused into reg-staging).
// Bt: bf16 (512 x 512) pre-transposed weights, gload_lds staging.
// z==0: C=qb (scaled by log2e/sqrt(SEQ)); z==1: C=kbuf; z==2: write vT transposed.
// Double-buffered; one barrier per K-step.

__global__ __launch_bounds__(256) void gemm_proj(const float* __restrict__ Aq,
                                                 const float* __restrict__ Ak,
                                                 const float* __restrict__ Av,
                                                 const unsigned short* __restrict__ WqT,
                                                 const unsigned short* __restrict__ WkT,
                                                 const unsigned short* __restrict__ WvT,
                                                 const float* __restrict__ bq,
                                                 const float* __restrict__ bk,
                                                 const float* __restrict__ bv,
                                                 unsigned short* __restrict__ qb,
                                                 unsigned short* __restrict__ kb,
                                                 unsigned short* __restrict__ vT,
                                                 float qscale) {
  // smem: lA = [0..8191] ([2][4096] bf16), lB = [8192..16383]; ldsT aliases all
  // (34816 B) for the z==2 transpose epilogue (after final barrier).
  __shared__ unsigned short smem[17408];
  unsigned short* lA = smem;
  unsigned short* lB = smem + 8192;

  const int z = blockIdx.z;
  const float* A32 = (z == 0) ? Aq : ((z == 1) ? Ak : Av);
  const unsigned short* Bt = (z == 0) ? WqT : ((z == 1) ? WkT : WvT);
  const float* bias = (z == 0) ? bq : ((z == 1) ? bk : bv);
  const float gs = (z == 0) ? qscale : 1.0f;

  const int tid = threadIdx.x;
  const int lane = tid & 63, wave = tid >> 6;
  const int wr = wave >> 1, wc = wave & 1;         // 2x2 wave grid
  const int row0 = blockIdx.x * 128, col0 = blockIdx.y * 128;
  const int lr = lane & 15, lg = lane >> 4;

  f32x4 acc[4][4] = {};

  // A reg-staging: seg0 = tid, seg1 = tid+256; row = seg>>2, k8 = (seg&3)*8.
  const int r0s = tid >> 2, k8s = (tid & 3) * 8;
  // B gload_lds chunks (512 per matrix, 2 per thread):
  const int s0a = wave * 64;
  const int sAi = s0a + lane, rA = sAi >> 2, koA = (sAi & 3) * 8;
  const int s0b = 256 + wave * 64;
  const int sBi = s0b + lane, rB = sBi >> 2, koB = (sBi & 3) * 8;

  float4 ra0, ra1, rb0, rb1;

#define LOADA(k0)                                                              \
  do {                                                                         \
    const float* p0 = A32 + (size_t)(row0 + r0s) * DIM + (k0) + k8s;           \
    ra0 = *reinterpret_cast<const float4*>(p0);                                \
    ra1 = *reinterpret_cast<const float4*>(p0 + 4);                            \
    const float* p1 = A32 + (size_t)(row0 + r0s + 64) * DIM + (k0) + k8s;      \
    rb0 = *reinterpret_cast<const float4*>(p1);                                \
    rb1 = *reinterpret_cast<const float4*>(p1 + 4);                            \
  } while (0)

#define WRITEA(buf)                                                            \
  do {                                                                         \
    *reinterpret_cast<bf16x8*>(&lA[(buf)*4096 + r0s * 32 + k8s]) = cvt8(ra0, ra1); \
    *reinterpret_cast<bf16x8*>(&lA[(buf)*4096 + (r0s + 64) * 32 + k8s]) = cvt8(rb0, rb1); \
  } while (0)

#define STAGEB(buf, k0)                                                        \
  do {                                                                         \
    gload_lds16(Bt + (size_t)(col0 + rA) * DIM + (k0) + koA, &lB[(buf)*4096 + s0a * 8]); \
    gload_lds16(Bt + (size_t)(col0 + rB) * DIM + (k0) + koB, &lB[(buf)*4096 + s0b * 8]); \
  } while (0)

  LOADA(0);
  STAGEB(0, 0);
  WRITEA(0);
  __syncthreads();

  constexpr int NT = DIM / 32;  // 16 K-steps
  for (int t = 0; t < NT; ++t) {
    const int cur = t & 1;
    if (t + 1 < NT) {
      LOADA((t + 1) * 32);
      STAGEB(cur ^ 1, (t + 1) * 32);
    }

    bf16x8 af[4], bfr[4];
#pragma unroll
    for (int m = 0; m < 4; ++m)
      af[m] = *reinterpret_cast<const bf16x8*>(&lA[cur * 4096 + (wr * 64 + m * 16 + lr) * 32 + lg * 8]);
#pragma unroll
    for (int n = 0; n < 4; ++n)
      bfr[n] = *reinterpret_cast<const bf16x8*>(&lB[cur * 4096 + (wc * 64 + n * 16 + lr) * 32 + lg * 8]);
    __builtin_amdgcn_s_setprio(1);
#pragma unroll
    for (int m = 0; m < 4; ++m)
#pragma unroll
      for (int n = 0; n < 4; ++n)
        acc[m][n] = __builtin_amdgcn_mfma_f32_16x16x32_bf16(af[m], bfr[n], acc[m][n], 0, 0, 0);
    __builtin_amdgcn_s_setprio(0);

    if (t + 1 < NT) WRITEA(cur ^ 1);
    __syncthreads();
  }
#undef LOADA
#undef WRITEA
#undef STAGEB

  if (z < 2) {
    // normal epilogue: bf16 C row-major [M][512]
    unsigned short* C = (z == 0) ? qb : kb;
#pragma unroll
    for (int m = 0; m < 4; ++m) {
#pragma unroll
      for (int n = 0; n < 4; ++n) {
        int col = col0 + wc * 64 + n * 16 + lr;
        int r0 = row0 + wr * 64 + m * 16 + lg * 4;
        float bvv = bias[col];
#pragma unroll
        for (int j = 0; j < 4; ++j)
          C[(size_t)(r0 + j) * DIM + col] = f2bf((acc[m][n][j] + bvv) * gs);
      }
    }
  } else {
    // V epilogue: transpose through LDS, write vT[(b*8+h)*64+dv][s].
    // ldsT[col_local][row_local], stride 136 elems (16B-aligned rows).
    unsigned short* ldsT = smem;
#pragma unroll
    for (int m = 0; m < 4; ++m) {
#pragma unroll
      for (int n = 0; n < 4; ++n) {
        const int col = wc * 64 + n * 16 + lr;
        const int r0l = wr * 64 + m * 16 + lg * 4;
        const float bvv = bias[col0 + col];
        ushort4 pk;
        pk.x = f2bf(acc[m][n][0] + bvv);
        pk.y = f2bf(acc[m][n][1] + bvv);
        pk.z = f2bf(acc[m][n][2] + bvv);
        pk.w = f2bf(acc[m][n][3] + bvv);
        *reinterpret_cast<ushort4*>(&ldsT[col * 136 + r0l]) = pk;
      }
    }
    __syncthreads();
    const int b = row0 >> 10, s_loc0 = row0 & 1023;
#pragma unroll
    for (int it = 0; it < 8; ++it) {
      int idx = it * 256 + tid;
      int c = idx >> 4, s8 = idx & 15;   // 16 chunks of 8 per column
      bf16x8 v = *reinterpret_cast<const bf16x8*>(&ldsT[c * 136 + s8 * 8]);
      *reinterpret_cast<bf16x8*>(
          vT + ((size_t)(b * DIM) + col0 + c) * SEQ + s_loc0 + s8 * 8) = v;
    }
  }
}

// ---------- output projection GEMM (bf16 A staged via gload_lds, fp32 out) ----------

__global__ __launch_bounds__(256) void gemm_out(const unsigned short* __restrict__ A,
                                                const unsigned short* __restrict__ Bt,
                                                const float* __restrict__ bias,
                                                float* __restrict__ C) {
  __shared__ unsigned short lA[2][128 * 32];
  __shared__ unsigned short lB[2][128 * 32];
  const int tid = threadIdx.x;
  const int lane = tid & 63, wave = tid >> 6;
  const int wr = wave >> 1, wc = wave & 1;
  const int row0 = blockIdx.x * 128, col0 = blockIdx.y * 128;
  const int lr = lane & 15, lg = lane >> 4;

  f32x4 acc[4][4] = {};

  const int s0a = wave * 64;
  const int sA = s0a + lane, rA = sA >> 2, koA = (sA & 3) * 8;
  const int s0b = 256 + wave * 64;
  const int sB = s0b + lane, rB = sB >> 2, koB = (sB & 3) * 8;

#define GEMM_STAGE(buf, k0)                                                        \
  do {                                                                             \
    gload_lds16(A + (size_t)(row0 + rA) * DIM + (k0) + koA, &lA[buf][s0a * 8]);    \
    gload_lds16(Bt + (size_t)(col0 + rA) * DIM + (k0) + koA, &lB[buf][s0a * 8]);   \
    gload_lds16(A + (size_t)(row0 + rB) * DIM + (k0) + koB, &lA[buf][s0b * 8]);    \
    gload_lds16(Bt + (size_t)(col0 + rB) * DIM + (k0) + koB, &lB[buf][s0b * 8]);   \
  } while (0)

  GEMM_STAGE(0, 0);
  __syncthreads();

  constexpr int NT = DIM / 32;
  for (int t = 0; t < NT; ++t) {
    const int cur = t & 1;
    if (t + 1 < NT) GEMM_STAGE(cur ^ 1, (t + 1) * 32);

    bf16x8 af[4], bfr[4];
#pragma unroll
    for (int m = 0; m < 4; ++m)
      af[m] = *reinterpret_cast<const bf16x8*>(&lA[cur][(wr * 64 + m * 16 + lr) * 32 + lg * 8]);
#pragma unroll
    for (int n = 0; n < 4; ++n)
      bfr[n] = *reinterpret_cast<const bf16x8*>(&lB[cur][(wc * 64 + n * 16 + lr) * 32 + lg * 8]);
    __builtin_amdgcn_s_setprio(1);
#pragma unroll
    for (int m = 0; m < 4; ++m)
#pragma unroll
      for (int n = 0; n < 4; ++n)
        acc[m][n] = __builtin_amdgcn_mfma_f32_16x16x32_bf16(af[m], bfr[n], acc[m][n], 0, 0, 0);
    __builtin_amdgcn_s_setprio(0);

    __syncthreads();
  }
#undef GEMM_STAGE

#pragma unroll
  for (int m = 0; m < 4; ++m) {
#pragma unroll
    for (int n = 0; n < 4; ++n) {
      int col = col0 + wc * 64 + n * 16 + lr;
      int r0 = row0 + wr * 64 + m * 16 + lg * 4;
      float bv = bias[col];
#pragma unroll
      for (int j = 0; j < 4; ++j)
        C[(size_t)(r0 + j) * DIM + col] = acc[m][n][j] + bv;
    }
  }
}

// ---------- flash attention v4 ----------
// grid (SEQ/128, NH, BB) = 512 blocks; block 512 = 8 waves, wave owns 16 q-rows.
// Double-buffered K/V staging; one __syncthreads per tile.
// Q pre-scaled by log2e/sqrt(SEQ) in projection; p = exp2(s) via v_exp_f32.

__global__ __launch_bounds__(512) void attn_kernel(const unsigned short* __restrict__ qb,
                                                   const unsigned short* __restrict__ kb,
                                                   const unsigned short* __restrict__ vT,
                                                   unsigned short* __restrict__ ctx) {
  __shared__ unsigned short lK[2][64 * 64];     // [key][d], XOR chunk-swizzled
  __shared__ unsigned short lV[2][64 * 64];     // [dv][key], XOR chunk-swizzled
  __shared__ unsigned short Pl[8][16 * 72];     // per-wave P [q][key], stride 72

  const int b = blockIdx.z, h = blockIdx.y;
  const int tid = threadIdx.x, lane = tid & 63, wave = tid >> 6;
  const int lr = lane & 15, lg = lane >> 4;
  const int q0 = blockIdx.x * 128 + wave * 16;

  // staging chunk mapping: 512 chunks per matrix, 1 K + 1 V chunk per thread
  const int sr = tid >> 3, sc = (tid & 7) ^ (sr & 7);
  const unsigned short* Kbase = kb + ((size_t)b * SEQ) * DIM + (size_t)h * HD;
  const unsigned short* Vbase = vT + (size_t)(b * NH + h) * HD * SEQ;

  // hoist Q fragments: rows q0+lr, d = c*32 + lg*8..+8
  bf16x8 qf0, qf1;
  {
    const unsigned short* qrow = qb + ((size_t)(b * SEQ) + q0 + lr) * DIM + h * HD;
    qf0 = *reinterpret_cast<const bf16x8*>(qrow + lg * 8);
    qf1 = *reinterpret_cast<const bf16x8*>(qrow + 32 + lg * 8);
  }

  float l_r[4] = {0.f, 0.f, 0.f, 0.f};
  f32x4 o_acc[4];
#pragma unroll
  for (int n = 0; n < 4; ++n) o_acc[n] = f32x4{0.f, 0.f, 0.f, 0.f};

  unsigned short* pw = Pl[wave];

  // prologue: stage tile 0 into buffer 0
  gload_lds16(Kbase + (size_t)sr * DIM + sc * 8, &lK[0][(wave * 64) * 8]);
  gload_lds16(Vbase + (size_t)sr * SEQ + sc * 8, &lV[0][(wave * 64) * 8]);
  __syncthreads();

  for (int t = 0; t < SEQ / 64; ++t) {
    const int cur = t & 1;
    if (t + 1 < SEQ / 64) {  // prefetch next tile into the other buffer
      const int nk = (t + 1) * 64;
      gload_lds16(Kbase + (size_t)(nk + sr) * DIM + sc * 8, &lK[cur ^ 1][(wave * 64) * 8]);
      gload_lds16(Vbase + (size_t)sr * SEQ + nk + sc * 8, &lV[cur ^ 1][(wave * 64) * 8]);
    }

    // QK^T: st[kt], q = q0+lg*4+j, key = kt*16+lr
    f32x4 st[4];
    __builtin_amdgcn_s_setprio(1);
#pragma unroll
    for (int kt = 0; kt < 4; ++kt) {
      const int row = kt * 16 + lr;
      const char* rbase = (const char*)&lK[cur][0] + row * 128;
      const int sw = (row & 7) << 4;
      bf16x8 kf0 = *reinterpret_cast<const bf16x8*>(rbase + ((lg * 16) ^ sw));
      bf16x8 kf1 = *reinterpret_cast<const bf16x8*>(rbase + ((64 + lg * 16) ^ sw));
      f32x4 a = {};
      a = __builtin_amdgcn_mfma_f32_16x16x32_bf16(qf0, kf0, a, 0, 0, 0);
      a = __builtin_amdgcn_mfma_f32_16x16x32_bf16(qf1, kf1, a, 0, 0, 0);
      st[kt] = a;
    }
    __builtin_amdgcn_s_setprio(0);

    // softmax numerator: p = 2^s (scale·log2e folded into Q projection)
#pragma unroll
    for (int j = 0; j < 4; ++j) {
      float p0 = fexp2(st[0][j]);
      float p1 = fexp2(st[1][j]);
      float p2 = fexp2(st[2][j]);
      float p3 = fexp2(st[3][j]);
      l_r[j] += (p0 + p1) + (p2 + p3);
      const int qrow = (lg * 4 + j) * 72;
      pw[qrow + lr] = f2bf(p0);
      pw[qrow + 16 + lr] = f2bf(p1);
      pw[qrow + 32 + lr] = f2bf(p2);
      pw[qrow + 48 + lr] = f2bf(p3);
    }

    // PV: o_acc[n] += P[q][k] V[k][dv]
#pragma unroll
    for (int c = 0; c < 2; ++c) {
      bf16x8 pf = *reinterpret_cast<const bf16x8*>((const char*)pw + lr * 144 + c * 64 + lg * 16);
      __builtin_amdgcn_s_setprio(1);
#pragma unroll
      for (int n = 0; n < 4; ++n) {
        const int row = n * 16 + lr;
        bf16x8 vf = *reinterpret_cast<const bf16x8*>(
            (const char*)&lV[cur][0] + row * 128 + ((c * 64 + lg * 16) ^ ((row & 7) << 4)));
        o_acc[n] = __builtin_amdgcn_mfma_f32_16x16x32_bf16(pf, vf, o_acc[n], 0, 0, 0);
      }
      __builtin_amdgcn_s_setprio(0);
    }

    __syncthreads();  // drains prefetch vmcnt + guards buffer reuse
  }

  // final l reduction + normalize, bounce through pw for coalesced stores
  float invl[4];
#pragma unroll
  for (int j = 0; j < 4; ++j) {
    float l = l_r[j];
#pragma unroll
    for (int msk = 1; msk < 16; msk <<= 1) l += __shfl_xor(l, msk);
    invl[j] = 1.f / l;
  }
#pragma unroll
  for (int n = 0; n < 4; ++n)
#pragma unroll
    for (int j = 0; j < 4; ++j)
      pw[(lg * 4 + j) * 72 + n * 16 + lr] = f2bf(o_acc[n][j] * invl[j]);

  // 16 rows x 8 chunks = 128 chunks per wave; 2 iters x 64 lanes.
#pragma unroll
  for (int it = 0; it < 2; ++it) {
    int idx = it * 64 + lane;
    int r = idx >> 3, cc = idx & 7;
    bf16x8 v = *reinterpret_cast<const bf16x8*>((const char*)pw + r * 144 + cc * 16);
    *reinterpret_cast<bf16x8*>(ctx + ((size_t)(b * SEQ) + q0 + r) * DIM + h * HD + cc * 8) = v;
  }
}

// ---------- launch ----------

extern "C" void kernel_launch(void* const* d_in, const int* in_sizes, int n_in,
                              void* d_out, int out_size, void* d_ws, size_t ws_size,
                              hipStream_t stream) {
  const float* query = (const float*)d_in[0];
  const float* key_  = (const float*)d_in[1];
  const float* value = (const float*)d_in[2];
  const float* Wq = (const float*)d_in[3];
  const float* bq = (const float*)d_in[4];
  const float* Wk = (const float*)d_in[5];
  const float* bk = (const float*)d_in[6];
  const float* Wv = (const float*)d_in[7];
  const float* bv = (const float*)d_in[8];
  const float* Wo = (const float*)d_in[9];
  const float* bo = (const float*)d_in[10];
  float* out = (float*)d_out;

  unsigned short* ws = (unsigned short*)d_ws;
  const size_t NM = (size_t)M * DIM;    // 4194304 elems
  const size_t NW = (size_t)DIM * DIM;  // 262144 elems
  unsigned short* qb   = ws;
  unsigned short* kbuf = qb + NM;
  unsigned short* vTb  = kbuf + NM;
  unsigned short* ctx  = vTb + NM;
  unsigned short* Wqt  = ctx + NM;
  unsigned short* Wkt  = Wqt + NW;
  unsigned short* Wvt  = Wkt + NW;
  unsigned short* Wot  = Wvt + NW;

  // weight converts (tiny)
  cvt_t4_kernel<<<dim3(16, 16, 4), 256, 0, stream>>>(Wq, Wk, Wv, Wo, Wqt, Wkt, Wvt, Wot);

  // fused projections: fp32 inputs converted during staging; V written transposed.
  // Q pre-scaled by log2e/sqrt(SEQ) for exp2-softmax.
  const float qscale = 0.03125f * 1.4426950408889634f;
  gemm_proj<<<dim3(M / 128, DIM / 128, 3), 256, 0, stream>>>(
      query, key_, value, Wqt, Wkt, Wvt, bq, bk, bv, qb, kbuf, vTb, qscale);

  // attention
  attn_kernel<<<dim3(SEQ / 128, NH, BB), 512, 0, stream>>>(qb, kbuf, vTb, ctx);

  // output projection (fp32 out + bias)
  gemm_out<<<dim3(M / 128, DIM / 128), 256, 0, stream>>>(ctx, Wot, bo, out);
}

// Round 8
// 86.225 us; speedup vs baseline: 1.0240x; 1.0240x over previous
//
#include <hip/hip_runtime.h>
#include <hip/hip_bf16.h>

#define DEVI __device__ __forceinline__

typedef __attribute__((ext_vector_type(4))) float f32x4;
typedef __attribute__((ext_vector_type(8))) short bf16x8;

static constexpr int BB  = 8;     // batch
static constexpr int SEQ = 1024;  // sequence length
static constexpr int DIM = 512;   // model dim = H*DQ
static constexpr int NH  = 8;     // heads
static constexpr int HD  = 64;    // head dim
static constexpr int M   = BB * SEQ;  // 8192 flattened rows

// ---------- helpers ----------

DEVI unsigned short f2bf(float x) {
  unsigned int u = __builtin_bit_cast(unsigned int, x);
  u += 0x7fffu + ((u >> 16) & 1u);
  return (unsigned short)(u >> 16);
}

DEVI float fexp2(float x) {
#if __has_builtin(__builtin_amdgcn_exp2f)
  return __builtin_amdgcn_exp2f(x);
#else
  float r; asm("v_exp_f32 %0, %1" : "=v"(r) : "v"(x)); return r;
#endif
}

DEVI void gload_lds16(const unsigned short* g, unsigned short* l) {
  __builtin_amdgcn_global_load_lds(
      (const __attribute__((address_space(1))) void*)g,
      (__attribute__((address_space(3))) void*)l, 16, 0, 0);
}

// ---------- fp32 -> bf16 convert: 3 tensors in one launch ----------

__global__ __launch_bounds__(256) void cvt3_kernel(const float* __restrict__ a,
                                                   const float* __restrict__ b,
                                                   const float* __restrict__ c,
                                                   unsigned short* __restrict__ oa,
                                                   unsigned short* __restrict__ ob,
                                                   unsigned short* __restrict__ oc) {
  const float* in = (blockIdx.y == 0) ? a : ((blockIdx.y == 1) ? b : c);
  unsigned short* out = (blockIdx.y == 0) ? oa : ((blockIdx.y == 1) ? ob : oc);
  int i = (blockIdx.x * 256 + threadIdx.x) * 4;
  float4 v = *reinterpret_cast<const float4*>(in + i);
  ushort4 o;
  o.x = f2bf(v.x); o.y = f2bf(v.y); o.z = f2bf(v.z); o.w = f2bf(v.w);
  *reinterpret_cast<ushort4*>(out + i) = o;
}

// ---------- fp32 (K x N) -> bf16 transposed (N x K), 4 weights in one launch ----------

__global__ __launch_bounds__(256) void cvt_t4_kernel(const float* __restrict__ w0,
                                                     const float* __restrict__ w1,
                                                     const float* __restrict__ w2,
                                                     const float* __restrict__ w3,
                                                     unsigned short* __restrict__ o0,
                                                     unsigned short* __restrict__ o1,
                                                     unsigned short* __restrict__ o2,
                                                     unsigned short* __restrict__ o3) {
  const float* in = (blockIdx.z == 0) ? w0 : ((blockIdx.z == 1) ? w1 : ((blockIdx.z == 2) ? w2 : w3));
  unsigned short* out = (blockIdx.z == 0) ? o0 : ((blockIdx.z == 1) ? o1 : ((blockIdx.z == 2) ? o2 : o3));
  __shared__ float tile[32][33];
  int n0 = blockIdx.x * 32, k0 = blockIdx.y * 32;
  int tx = threadIdx.x & 31, ty = threadIdx.x >> 5;  // 32 x 8
#pragma unroll
  for (int r = 0; r < 32; r += 8)
    tile[ty + r][tx] = in[(size_t)(k0 + ty + r) * DIM + n0 + tx];
  __syncthreads();
#pragma unroll
  for (int r = 0; r < 32; r += 8)
    out[(size_t)(n0 + ty + r) * DIM + k0 + tx] = f2bf(tile[tx][ty + r]);
}

// ---------- fused projection GEMM (bf16 A via gload_lds, dbuf) ----------
// z==0: C=qb scaled; z==1: C=kbuf; z==2: V written TRANSPOSED to vT via LDS bounce.

__global__ __launch_bounds__(256) void gemm_proj(const unsigned short* __restrict__ Aq,
                                                 const unsigned short* __restrict__ Ak,
                                                 const unsigned short* __restrict__ Av,
                                                 const unsigned short* __restrict__ WqT,
                                                 const unsigned short* __restrict__ WkT,
                                                 const unsigned short* __restrict__ WvT,
                                                 const float* __restrict__ bq,
                                                 const float* __restrict__ bk,
                                                 const float* __restrict__ bv,
                                                 unsigned short* __restrict__ qb,
                                                 unsigned short* __restrict__ kb,
                                                 unsigned short* __restrict__ vT,
                                                 float qscale) {
  // smem: lA[2][4096] = [0..8191], lB[2][4096] = [8192..16383] (32KB staging);
  // ldsT (z==2 epilogue) aliases everything: 128 * 136 * 2B = 34816 B.
  __shared__ unsigned short smem[17408];
  unsigned short* lA = smem;
  unsigned short* lB = smem + 8192;

  const int z = blockIdx.z;
  const unsigned short* A = (z == 0) ? Aq : ((z == 1) ? Ak : Av);
  const unsigned short* Bt = (z == 0) ? WqT : ((z == 1) ? WkT : WvT);
  const float* bias = (z == 0) ? bq : ((z == 1) ? bk : bv);
  const float gs = (z == 0) ? qscale : 1.0f;

  const int tid = threadIdx.x;
  const int lane = tid & 63, wave = tid >> 6;
  const int wr = wave >> 1, wc = wave & 1;         // 2x2 wave grid
  const int row0 = blockIdx.x * 128, col0 = blockIdx.y * 128;
  const int lr = lane & 15, lg = lane >> 4;

  f32x4 acc[4][4] = {};

  // staging: 512 16B-chunks per matrix; 2 wave-instructions each
  const int s0a = wave * 64;
  const int sA = s0a + lane, rA = sA >> 2, koA = (sA & 3) * 8;
  const int s0b = 256 + wave * 64;
  const int sB = s0b + lane, rB = sB >> 2, koB = (sB & 3) * 8;

#define GEMM_STAGE(buf, k0)                                                              \
  do {                                                                                   \
    gload_lds16(A + (size_t)(row0 + rA) * DIM + (k0) + koA, &lA[(buf)*4096 + s0a * 8]);  \
    gload_lds16(Bt + (size_t)(col0 + rA) * DIM + (k0) + koA, &lB[(buf)*4096 + s0a * 8]); \
    gload_lds16(A + (size_t)(row0 + rB) * DIM + (k0) + koB, &lA[(buf)*4096 + s0b * 8]);  \
    gload_lds16(Bt + (size_t)(col0 + rB) * DIM + (k0) + koB, &lB[(buf)*4096 + s0b * 8]); \
  } while (0)

  GEMM_STAGE(0, 0);
  __syncthreads();

  constexpr int NT = DIM / 32;  // 16 K-steps
  for (int t = 0; t < NT; ++t) {
    const int cur = t & 1;
    if (t + 1 < NT) GEMM_STAGE(cur ^ 1, (t + 1) * 32);

    bf16x8 af[4], bfr[4];
#pragma unroll
    for (int m = 0; m < 4; ++m)
      af[m] = *reinterpret_cast<const bf16x8*>(&lA[cur * 4096 + (wr * 64 + m * 16 + lr) * 32 + lg * 8]);
#pragma unroll
    for (int n = 0; n < 4; ++n)
      bfr[n] = *reinterpret_cast<const bf16x8*>(&lB[cur * 4096 + (wc * 64 + n * 16 + lr) * 32 + lg * 8]);
    __builtin_amdgcn_s_setprio(1);
#pragma unroll
    for (int m = 0; m < 4; ++m)
#pragma unroll
      for (int n = 0; n < 4; ++n)
        acc[m][n] = __builtin_amdgcn_mfma_f32_16x16x32_bf16(af[m], bfr[n], acc[m][n], 0, 0, 0);
    __builtin_amdgcn_s_setprio(0);

    __syncthreads();  // retires prefetch (vmcnt0) + guards buffer reuse
  }
#undef GEMM_STAGE

  if (z < 2) {
    // normal epilogue: bf16 C row-major [M][512]
    unsigned short* C = (z == 0) ? qb : kb;
#pragma unroll
    for (int m = 0; m < 4; ++m) {
#pragma unroll
      for (int n = 0; n < 4; ++n) {
        int col = col0 + wc * 64 + n * 16 + lr;
        int r0 = row0 + wr * 64 + m * 16 + lg * 4;
        float bvv = bias[col];
#pragma unroll
        for (int j = 0; j < 4; ++j)
          C[(size_t)(r0 + j) * DIM + col] = f2bf((acc[m][n][j] + bvv) * gs);
      }
    }
  } else {
    // V epilogue: transpose through LDS, write vT[(b*8+h)*64+dv][s].
    // ldsT[col_local][row_local], stride 136 elems (16B-aligned rows).
    unsigned short* ldsT = smem;
#pragma unroll
    for (int m = 0; m < 4; ++m) {
#pragma unroll
      for (int n = 0; n < 4; ++n) {
        const int col = wc * 64 + n * 16 + lr;
        const int r0l = wr * 64 + m * 16 + lg * 4;
        const float bvv = bias[col0 + col];
        ushort4 pk;
        pk.x = f2bf(acc[m][n][0] + bvv);
        pk.y = f2bf(acc[m][n][1] + bvv);
        pk.z = f2bf(acc[m][n][2] + bvv);
        pk.w = f2bf(acc[m][n][3] + bvv);
        *reinterpret_cast<ushort4*>(&ldsT[col * 136 + r0l]) = pk;
      }
    }
    __syncthreads();
    const int b = row0 >> 10, s_loc0 = row0 & 1023;
#pragma unroll
    for (int it = 0; it < 8; ++it) {
      int idx = it * 256 + tid;
      int c = idx >> 4, s8 = idx & 15;   // 16 chunks of 8 per column
      bf16x8 v = *reinterpret_cast<const bf16x8*>(&ldsT[c * 136 + s8 * 8]);
      *reinterpret_cast<bf16x8*>(
          vT + ((size_t)(b * DIM) + col0 + c) * SEQ + s_loc0 + s8 * 8) = v;
    }
  }
}

// ---------- output projection GEMM (bf16 A staged via gload_lds, fp32 out) ----------

__global__ __launch_bounds__(256) void gemm_out(const unsigned short* __restrict__ A,
                                                const unsigned short* __restrict__ Bt,
                                                const float* __restrict__ bias,
                                                float* __restrict__ C) {
  __shared__ unsigned short lA[2][128 * 32];
  __shared__ unsigned short lB[2][128 * 32];
  const int tid = threadIdx.x;
  const int lane = tid & 63, wave = tid >> 6;
  const int wr = wave >> 1, wc = wave & 1;
  const int row0 = blockIdx.x * 128, col0 = blockIdx.y * 128;
  const int lr = lane & 15, lg = lane >> 4;

  f32x4 acc[4][4] = {};

  const int s0a = wave * 64;
  const int sA = s0a + lane, rA = sA >> 2, koA = (sA & 3) * 8;
  const int s0b = 256 + wave * 64;
  const int sB = s0b + lane, rB = sB >> 2, koB = (sB & 3) * 8;

#define GEMM_STAGE(buf, k0)                                                        \
  do {                                                                             \
    gload_lds16(A + (size_t)(row0 + rA) * DIM + (k0) + koA, &lA[buf][s0a * 8]);    \
    gload_lds16(Bt + (size_t)(col0 + rA) * DIM + (k0) + koA, &lB[buf][s0a * 8]);   \
    gload_lds16(A + (size_t)(row0 + rB) * DIM + (k0) + koB, &lA[buf][s0b * 8]);    \
    gload_lds16(Bt + (size_t)(col0 + rB) * DIM + (k0) + koB, &lB[buf][s0b * 8]);   \
  } while (0)

  GEMM_STAGE(0, 0);
  __syncthreads();

  constexpr int NT = DIM / 32;
  for (int t = 0; t < NT; ++t) {
    const int cur = t & 1;
    if (t + 1 < NT) GEMM_STAGE(cur ^ 1, (t + 1) * 32);

    bf16x8 af[4], bfr[4];
#pragma unroll
    for (int m = 0; m < 4; ++m)
      af[m] = *reinterpret_cast<const bf16x8*>(&lA[cur][(wr * 64 + m * 16 + lr) * 32 + lg * 8]);
#pragma unroll
    for (int n = 0; n < 4; ++n)
      bfr[n] = *reinterpret_cast<const bf16x8*>(&lB[cur][(wc * 64 + n * 16 + lr) * 32 + lg * 8]);
    __builtin_amdgcn_s_setprio(1);
#pragma unroll
    for (int m = 0; m < 4; ++m)
#pragma unroll
      for (int n = 0; n < 4; ++n)
        acc[m][n] = __builtin_amdgcn_mfma_f32_16x16x32_bf16(af[m], bfr[n], acc[m][n], 0, 0, 0);
    __builtin_amdgcn_s_setprio(0);

    __syncthreads();
  }
#undef GEMM_STAGE

#pragma unroll
  for (int m = 0; m < 4; ++m) {
#pragma unroll
    for (int n = 0; n < 4; ++n) {
      int col = col0 + wc * 64 + n * 16 + lr;
      int r0 = row0 + wr * 64 + m * 16 + lg * 4;
      float bv = bias[col];
#pragma unroll
      for (int j = 0; j < 4; ++j)
        C[(size_t)(r0 + j) * DIM + col] = acc[m][n][j] + bv;
    }
  }
}

// ---------- flash attention v4 ----------
// grid (SEQ/128, NH, BB) = 512 blocks; block 512 = 8 waves, wave owns 16 q-rows.
// Double-buffered K/V staging; one __syncthreads per tile.
// Q pre-scaled by log2e/sqrt(SEQ) in projection; p = exp2(s) via v_exp_f32.

__global__ __launch_bounds__(512) void attn_kernel(const unsigned short* __restrict__ qb,
                                                   const unsigned short* __restrict__ kb,
                                                   const unsigned short* __restrict__ vT,
                                                   unsigned short* __restrict__ ctx) {
  __shared__ unsigned short lK[2][64 * 64];     // [key][d], XOR chunk-swizzled
  __shared__ unsigned short lV[2][64 * 64];     // [dv][key], XOR chunk-swizzled
  __shared__ unsigned short Pl[8][16 * 72];     // per-wave P [q][key], stride 72

  const int b = blockIdx.z, h = blockIdx.y;
  const int tid = threadIdx.x, lane = tid & 63, wave = tid >> 6;
  const int lr = lane & 15, lg = lane >> 4;
  const int q0 = blockIdx.x * 128 + wave * 16;

  // staging chunk mapping: 512 chunks per matrix, 1 K + 1 V chunk per thread
  const int sr = tid >> 3, sc = (tid & 7) ^ (sr & 7);
  const unsigned short* Kbase = kb + ((size_t)b * SEQ) * DIM + (size_t)h * HD;
  const unsigned short* Vbase = vT + (size_t)(b * NH + h) * HD * SEQ;

  // hoist Q fragments: rows q0+lr, d = c*32 + lg*8..+8
  bf16x8 qf0, qf1;
  {
    const unsigned short* qrow = qb + ((size_t)(b * SEQ) + q0 + lr) * DIM + h * HD;
    qf0 = *reinterpret_cast<const bf16x8*>(qrow + lg * 8);
    qf1 = *reinterpret_cast<const bf16x8*>(qrow + 32 + lg * 8);
  }

  float l_r[4] = {0.f, 0.f, 0.f, 0.f};
  f32x4 o_acc[4];
#pragma unroll
  for (int n = 0; n < 4; ++n) o_acc[n] = f32x4{0.f, 0.f, 0.f, 0.f};

  unsigned short* pw = Pl[wave];

  // prologue: stage tile 0 into buffer 0
  gload_lds16(Kbase + (size_t)sr * DIM + sc * 8, &lK[0][(wave * 64) * 8]);
  gload_lds16(Vbase + (size_t)sr * SEQ + sc * 8, &lV[0][(wave * 64) * 8]);
  __syncthreads();

  for (int t = 0; t < SEQ / 64; ++t) {
    const int cur = t & 1;
    if (t + 1 < SEQ / 64) {  // prefetch next tile into the other buffer
      const int nk = (t + 1) * 64;
      gload_lds16(Kbase + (size_t)(nk + sr) * DIM + sc * 8, &lK[cur ^ 1][(wave * 64) * 8]);
      gload_lds16(Vbase + (size_t)sr * SEQ + nk + sc * 8, &lV[cur ^ 1][(wave * 64) * 8]);
    }

    // QK^T: st[kt], q = q0+lg*4+j, key = kt*16+lr
    f32x4 st[4];
    __builtin_amdgcn_s_setprio(1);
#pragma unroll
    for (int kt = 0; kt < 4; ++kt) {
      const int row = kt * 16 + lr;
      const char* rbase = (const char*)&lK[cur][0] + row * 128;
      const int sw = (row & 7) << 4;
      bf16x8 kf0 = *reinterpret_cast<const bf16x8*>(rbase + ((lg * 16) ^ sw));
      bf16x8 kf1 = *reinterpret_cast<const bf16x8*>(rbase + ((64 + lg * 16) ^ sw));
      f32x4 a = {};
      a = __builtin_amdgcn_mfma_f32_16x16x32_bf16(qf0, kf0, a, 0, 0, 0);
      a = __builtin_amdgcn_mfma_f32_16x16x32_bf16(qf1, kf1, a, 0, 0, 0);
      st[kt] = a;
    }
    __builtin_amdgcn_s_setprio(0);

    // softmax numerator: p = 2^s (scale·log2e folded into Q projection)
#pragma unroll
    for (int j = 0; j < 4; ++j) {
      float p0 = fexp2(st[0][j]);
      float p1 = fexp2(st[1][j]);
      float p2 = fexp2(st[2][j]);
      float p3 = fexp2(st[3][j]);
      l_r[j] += (p0 + p1) + (p2 + p3);
      const int qrow = (lg * 4 + j) * 72;
      pw[qrow + lr] = f2bf(p0);
      pw[qrow + 16 + lr] = f2bf(p1);
      pw[qrow + 32 + lr] = f2bf(p2);
      pw[qrow + 48 + lr] = f2bf(p3);
    }

    // PV: o_acc[n] += P[q][k] V[k][dv]
#pragma unroll
    for (int c = 0; c < 2; ++c) {
      bf16x8 pf = *reinterpret_cast<const bf16x8*>((const char*)pw + lr * 144 + c * 64 + lg * 16);
      __builtin_amdgcn_s_setprio(1);
#pragma unroll
      for (int n = 0; n < 4; ++n) {
        const int row = n * 16 + lr;
        bf16x8 vf = *reinterpret_cast<const bf16x8*>(
            (const char*)&lV[cur][0] + row * 128 + ((c * 64 + lg * 16) ^ ((row & 7) << 4)));
        o_acc[n] = __builtin_amdgcn_mfma_f32_16x16x32_bf16(pf, vf, o_acc[n], 0, 0, 0);
      }
      __builtin_amdgcn_s_setprio(0);
    }

    __syncthreads();  // drains prefetch vmcnt + guards buffer reuse
  }

  // final l reduction + normalize, bounce through pw for coalesced stores
  float invl[4];
#pragma unroll
  for (int j = 0; j < 4; ++j) {
    float l = l_r[j];
#pragma unroll
    for (int msk = 1; msk < 16; msk <<= 1) l += __shfl_xor(l, msk);
    invl[j] = 1.f / l;
  }
#pragma unroll
  for (int n = 0; n < 4; ++n)
#pragma unroll
    for (int j = 0; j < 4; ++j)
      pw[(lg * 4 + j) * 72 + n * 16 + lr] = f2bf(o_acc[n][j] * invl[j]);

  // 16 rows x 8 chunks = 128 chunks per wave; 2 iters x 64 lanes.
#pragma unroll
  for (int it = 0; it < 2; ++it) {
    int idx = it * 64 + lane;
    int r = idx >> 3, cc = idx & 7;
    bf16x8 v = *reinterpret_cast<const bf16x8*>((const char*)pw + r * 144 + cc * 16);
    *reinterpret_cast<bf16x8*>(ctx + ((size_t)(b * SEQ) + q0 + r) * DIM + h * HD + cc * 8) = v;
  }
}

// ---------- launch ----------

extern "C" void kernel_launch(void* const* d_in, const int* in_sizes, int n_in,
                              void* d_out, int out_size, void* d_ws, size_t ws_size,
                              hipStream_t stream) {
  const float* query = (const float*)d_in[0];
  const float* key_  = (const float*)d_in[1];
  const float* value = (const float*)d_in[2];
  const float* Wq = (const float*)d_in[3];
  const float* bq = (const float*)d_in[4];
  const float* Wk = (const float*)d_in[5];
  const float* bk = (const float*)d_in[6];
  const float* Wv = (const float*)d_in[7];
  const float* bv = (const float*)d_in[8];
  const float* Wo = (const float*)d_in[9];
  const float* bo = (const float*)d_in[10];
  float* out = (float*)d_out;

  unsigned short* ws = (unsigned short*)d_ws;
  const size_t NM = (size_t)M * DIM;    // 4194304 elems
  const size_t NW = (size_t)DIM * DIM;  // 262144 elems
  unsigned short* xq   = ws;
  unsigned short* xk   = xq + NM;
  unsigned short* xv   = xk + NM;
  unsigned short* qb   = xv + NM;
  unsigned short* kbuf = qb + NM;
  unsigned short* vTb  = kbuf + NM;
  unsigned short* ctx  = vTb + NM;
  unsigned short* Wqt  = ctx + NM;
  unsigned short* Wkt  = Wqt + NW;
  unsigned short* Wvt  = Wkt + NW;
  unsigned short* Wot  = Wvt + NW;

  // converts
  cvt3_kernel<<<dim3((int)(NM / 1024), 3), 256, 0, stream>>>(query, key_, value, xq, xk, xv);
  cvt_t4_kernel<<<dim3(16, 16, 4), 256, 0, stream>>>(Wq, Wk, Wv, Wo, Wqt, Wkt, Wvt, Wot);

  // fused projections (bf16 A, gload_lds dbuf; V written transposed in epilogue).
  // Q pre-scaled by log2e/sqrt(SEQ) for exp2-softmax.
  const float qscale = 0.03125f * 1.4426950408889634f;
  gemm_proj<<<dim3(M / 128, DIM / 128, 3), 256, 0, stream>>>(
      xq, xk, xv, Wqt, Wkt, Wvt, bq, bk, bv, qb, kbuf, vTb, qscale);

  // attention
  attn_kernel<<<dim3(SEQ / 128, NH, BB), 512, 0, stream>>>(qb, kbuf, vTb, ctx);

  // output projection (fp32 out + bias)
  gemm_out<<<dim3(M / 128, DIM / 128), 256, 0, stream>>>(ctx, Wot, bo, out);
}

// Round 9
// 81.365 us; speedup vs baseline: 1.0851x; 1.0597x over previous
//
#include <hip/hip_runtime.h>
#include <hip/hip_bf16.h>

#define DEVI __device__ __forceinline__

typedef __attribute__((ext_vector_type(4))) float f32x4;
typedef __attribute__((ext_vector_type(8))) short bf16x8;

static constexpr int BB  = 8;     // batch
static constexpr int SEQ = 1024;  // sequence length
static constexpr int DIM = 512;   // model dim = H*DQ
static constexpr int NH  = 8;     // heads
static constexpr int HD  = 64;    // head dim
static constexpr int M   = BB * SEQ;  // 8192 flattened rows

// ---------- helpers ----------

DEVI unsigned short f2bf(float x) {
  unsigned int u = __builtin_bit_cast(unsigned int, x);
  u += 0x7fffu + ((u >> 16) & 1u);
  return (unsigned short)(u >> 16);
}

DEVI float fexp2(float x) {
#if __has_builtin(__builtin_amdgcn_exp2f)
  return __builtin_amdgcn_exp2f(x);
#else
  float r; asm("v_exp_f32 %0, %1" : "=v"(r) : "v"(x)); return r;
#endif
}

DEVI void gload_lds16(const unsigned short* g, unsigned short* l) {
  __builtin_amdgcn_global_load_lds(
      (const __attribute__((address_space(1))) void*)g,
      (__attribute__((address_space(3))) void*)l, 16, 0, 0);
}

// ---------- fp32 -> bf16 convert: 3 tensors in one launch ----------

__global__ __launch_bounds__(256) void cvt3_kernel(const float* __restrict__ a,
                                                   const float* __restrict__ b,
                                                   const float* __restrict__ c,
                                                   unsigned short* __restrict__ oa,
                                                   unsigned short* __restrict__ ob,
                                                   unsigned short* __restrict__ oc) {
  const float* in = (blockIdx.y == 0) ? a : ((blockIdx.y == 1) ? b : c);
  unsigned short* out = (blockIdx.y == 0) ? oa : ((blockIdx.y == 1) ? ob : oc);
  int i = (blockIdx.x * 256 + threadIdx.x) * 4;
  float4 v = *reinterpret_cast<const float4*>(in + i);
  ushort4 o;
  o.x = f2bf(v.x); o.y = f2bf(v.y); o.z = f2bf(v.z); o.w = f2bf(v.w);
  *reinterpret_cast<ushort4*>(out + i) = o;
}

// ---------- fp32 (K x N) -> bf16 transposed (N x K), 4 weights in one launch ----------

__global__ __launch_bounds__(256) void cvt_t4_kernel(const float* __restrict__ w0,
                                                     const float* __restrict__ w1,
                                                     const float* __restrict__ w2,
                                                     const float* __restrict__ w3,
                                                     unsigned short* __restrict__ o0,
                                                     unsigned short* __restrict__ o1,
                                                     unsigned short* __restrict__ o2,
                                                     unsigned short* __restrict__ o3) {
  const float* in = (blockIdx.z == 0) ? w0 : ((blockIdx.z == 1) ? w1 : ((blockIdx.z == 2) ? w2 : w3));
  unsigned short* out = (blockIdx.z == 0) ? o0 : ((blockIdx.z == 1) ? o1 : ((blockIdx.z == 2) ? o2 : o3));
  __shared__ float tile[32][33];
  int n0 = blockIdx.x * 32, k0 = blockIdx.y * 32;
  int tx = threadIdx.x & 31, ty = threadIdx.x >> 5;  // 32 x 8
#pragma unroll
  for (int r = 0; r < 32; r += 8)
    tile[ty + r][tx] = in[(size_t)(k0 + ty + r) * DIM + n0 + tx];
  __syncthreads();
#pragma unroll
  for (int r = 0; r < 32; r += 8)
    out[(size_t)(n0 + ty + r) * DIM + k0 + tx] = f2bf(tile[tx][ty + r]);
}

// ---------- fused projection GEMM ----------
// 3-buffer, 2-deep counted-vmcnt pipeline (T4): per step STAGE(t+2) ->
// vmcnt(8) -> s_barrier -> ds_read+MFMA -> s_barrier. Loads for t+1/t+2 stay
// in flight across barriers. Per-wave loads per stage = 4 -> vmcnt(8) means
// "two stages may remain outstanding".
// z==0: C=qb scaled; z==1: C=kbuf; z==2: V written TRANSPOSED to vT via LDS bounce.

__global__ __launch_bounds__(256) void gemm_proj(const unsigned short* __restrict__ Aq,
                                                 const unsigned short* __restrict__ Ak,
                                                 const unsigned short* __restrict__ Av,
                                                 const unsigned short* __restrict__ WqT,
                                                 const unsigned short* __restrict__ WkT,
                                                 const unsigned short* __restrict__ WvT,
                                                 const float* __restrict__ bq,
                                                 const float* __restrict__ bk,
                                                 const float* __restrict__ bv,
                                                 unsigned short* __restrict__ qb,
                                                 unsigned short* __restrict__ kb,
                                                 unsigned short* __restrict__ vT,
                                                 float qscale) {
  // smem: lA[3][4096] bf16 + lB[3][4096] bf16 = 49152 B; ldsT (z==2 epilogue,
  // 34816 B) aliases the front.
  __shared__ unsigned short smem[24576];
  unsigned short* lA = smem;
  unsigned short* lB = smem + 12288;

  const int z = blockIdx.z;
  const unsigned short* A = (z == 0) ? Aq : ((z == 1) ? Ak : Av);
  const unsigned short* Bt = (z == 0) ? WqT : ((z == 1) ? WkT : WvT);
  const float* bias = (z == 0) ? bq : ((z == 1) ? bk : bv);
  const float gs = (z == 0) ? qscale : 1.0f;

  const int tid = threadIdx.x;
  const int lane = tid & 63, wave = tid >> 6;
  const int wr = wave >> 1, wc = wave & 1;         // 2x2 wave grid
  const int row0 = blockIdx.x * 128, col0 = blockIdx.y * 128;
  const int lr = lane & 15, lg = lane >> 4;

  f32x4 acc[4][4] = {};

  // staging: 512 16B-chunks per matrix; 2 wave-instructions each matrix
  const int s0a = wave * 64;
  const int sA = s0a + lane, rA = sA >> 2, koA = (sA & 3) * 8;
  const int s0b = 256 + wave * 64;
  const int sB = s0b + lane, rB = sB >> 2, koB = (sB & 3) * 8;

#define GEMM_STAGE(buf, k0)                                                              \
  do {                                                                                   \
    gload_lds16(A + (size_t)(row0 + rA) * DIM + (k0) + koA, &lA[(buf)*4096 + s0a * 8]);  \
    gload_lds16(Bt + (size_t)(col0 + rA) * DIM + (k0) + koA, &lB[(buf)*4096 + s0a * 8]); \
    gload_lds16(A + (size_t)(row0 + rB) * DIM + (k0) + koB, &lA[(buf)*4096 + s0b * 8]);  \
    gload_lds16(Bt + (size_t)(col0 + rB) * DIM + (k0) + koB, &lB[(buf)*4096 + s0b * 8]); \
  } while (0)

#define GEMM_STEP(cur, VMC)                                                              \
  do {                                                                                   \
    asm volatile("s_waitcnt vmcnt(" #VMC ")" ::: "memory");                              \
    __builtin_amdgcn_s_barrier();                                                        \
    bf16x8 af[4], bfr[4];                                                                \
    _Pragma("unroll")                                                                    \
    for (int m = 0; m < 4; ++m)                                                          \
      af[m] = *reinterpret_cast<const bf16x8*>(&lA[(cur)*4096 + (wr * 64 + m * 16 + lr) * 32 + lg * 8]); \
    _Pragma("unroll")                                                                    \
    for (int n = 0; n < 4; ++n)                                                          \
      bfr[n] = *reinterpret_cast<const bf16x8*>(&lB[(cur)*4096 + (wc * 64 + n * 16 + lr) * 32 + lg * 8]); \
    __builtin_amdgcn_s_setprio(1);                                                       \
    _Pragma("unroll")                                                                    \
    for (int m = 0; m < 4; ++m)                                                          \
      _Pragma("unroll")                                                                  \
      for (int n = 0; n < 4; ++n)                                                        \
        acc[m][n] = __builtin_amdgcn_mfma_f32_16x16x32_bf16(af[m], bfr[n], acc[m][n], 0, 0, 0); \
    __builtin_amdgcn_s_setprio(0);                                                       \
    asm volatile("" ::: "memory");                                                       \
    __builtin_amdgcn_s_barrier();                                                        \
  } while (0)

  constexpr int NT = DIM / 32;  // 16 K-steps
  GEMM_STAGE(0, 0);
  GEMM_STAGE(1, 32);
  for (int t = 0; t < NT - 2; ++t) {
    GEMM_STAGE((t + 2) % 3, (t + 2) * 32);
    GEMM_STEP(t % 3, 8);
  }
  GEMM_STEP((NT - 2) % 3, 4);
  GEMM_STEP((NT - 1) % 3, 0);
#undef GEMM_STAGE
#undef GEMM_STEP

  if (z < 2) {
    // normal epilogue: bf16 C row-major [M][512]
    unsigned short* C = (z == 0) ? qb : kb;
#pragma unroll
    for (int m = 0; m < 4; ++m) {
#pragma unroll
      for (int n = 0; n < 4; ++n) {
        int col = col0 + wc * 64 + n * 16 + lr;
        int r0 = row0 + wr * 64 + m * 16 + lg * 4;
        float bvv = bias[col];
#pragma unroll
        for (int j = 0; j < 4; ++j)
          C[(size_t)(r0 + j) * DIM + col] = f2bf((acc[m][n][j] + bvv) * gs);
      }
    }
  } else {
    // V epilogue: transpose through LDS, write vT[(b*8+h)*64+dv][s].
    // ldsT[col_local][row_local], stride 136 elems (16B-aligned rows).
    unsigned short* ldsT = smem;
    __syncthreads();  // all MFMA-phase LDS reads done before overwrite
#pragma unroll
    for (int m = 0; m < 4; ++m) {
#pragma unroll
      for (int n = 0; n < 4; ++n) {
        const int col = wc * 64 + n * 16 + lr;
        const int r0l = wr * 64 + m * 16 + lg * 4;
        const float bvv = bias[col0 + col];
        ushort4 pk;
        pk.x = f2bf(acc[m][n][0] + bvv);
        pk.y = f2bf(acc[m][n][1] + bvv);
        pk.z = f2bf(acc[m][n][2] + bvv);
        pk.w = f2bf(acc[m][n][3] + bvv);
        *reinterpret_cast<ushort4*>(&ldsT[col * 136 + r0l]) = pk;
      }
    }
    __syncthreads();
    const int b = row0 >> 10, s_loc0 = row0 & 1023;
#pragma unroll
    for (int it = 0; it < 8; ++it) {
      int idx = it * 256 + tid;
      int c = idx >> 4, s8 = idx & 15;   // 16 chunks of 8 per column
      bf16x8 v = *reinterpret_cast<const bf16x8*>(&ldsT[c * 136 + s8 * 8]);
      *reinterpret_cast<bf16x8*>(
          vT + ((size_t)(b * DIM) + col0 + c) * SEQ + s_loc0 + s8 * 8) = v;
    }
  }
}

// ---------- output projection GEMM (same counted-vmcnt pipeline, fp32 out) ----------

__global__ __launch_bounds__(256) void gemm_out(const unsigned short* __restrict__ A,
                                                const unsigned short* __restrict__ Bt,
                                                const float* __restrict__ bias,
                                                float* __restrict__ C) {
  __shared__ unsigned short lA[3][128 * 32];
  __shared__ unsigned short lB[3][128 * 32];
  const int tid = threadIdx.x;
  const int lane = tid & 63, wave = tid >> 6;
  const int wr = wave >> 1, wc = wave & 1;
  const int row0 = blockIdx.x * 128, col0 = blockIdx.y * 128;
  const int lr = lane & 15, lg = lane >> 4;

  f32x4 acc[4][4] = {};

  const int s0a = wave * 64;
  const int sA = s0a + lane, rA = sA >> 2, koA = (sA & 3) * 8;
  const int s0b = 256 + wave * 64;
  const int sB = s0b + lane, rB = sB >> 2, koB = (sB & 3) * 8;

#define GEMM_STAGE(buf, k0)                                                        \
  do {                                                                             \
    gload_lds16(A + (size_t)(row0 + rA) * DIM + (k0) + koA, &lA[buf][s0a * 8]);    \
    gload_lds16(Bt + (size_t)(col0 + rA) * DIM + (k0) + koA, &lB[buf][s0a * 8]);   \
    gload_lds16(A + (size_t)(row0 + rB) * DIM + (k0) + koB, &lA[buf][s0b * 8]);    \
    gload_lds16(Bt + (size_t)(col0 + rB) * DIM + (k0) + koB, &lB[buf][s0b * 8]);   \
  } while (0)

#define GEMM_STEP(cur, VMC)                                                        \
  do {                                                                             \
    asm volatile("s_waitcnt vmcnt(" #VMC ")" ::: "memory");                        \
    __builtin_amdgcn_s_barrier();                                                  \
    bf16x8 af[4], bfr[4];                                                          \
    _Pragma("unroll")                                                              \
    for (int m = 0; m < 4; ++m)                                                    \
      af[m] = *reinterpret_cast<const bf16x8*>(&lA[cur][(wr * 64 + m * 16 + lr) * 32 + lg * 8]); \
    _Pragma("unroll")                                                              \
    for (int n = 0; n < 4; ++n)                                                    \
      bfr[n] = *reinterpret_cast<const bf16x8*>(&lB[cur][(wc * 64 + n * 16 + lr) * 32 + lg * 8]); \
    __builtin_amdgcn_s_setprio(1);                                                 \
    _Pragma("unroll")                                                              \
    for (int m = 0; m < 4; ++m)                                                    \
      _Pragma("unroll")                                                            \
      for (int n = 0; n < 4; ++n)                                                  \
        acc[m][n] = __builtin_amdgcn_mfma_f32_16x16x32_bf16(af[m], bfr[n], acc[m][n], 0, 0, 0); \
    __builtin_amdgcn_s_setprio(0);                                                 \
    asm volatile("" ::: "memory");                                                 \
    __builtin_amdgcn_s_barrier();                                                  \
  } while (0)

  constexpr int NT = DIM / 32;
  GEMM_STAGE(0, 0);
  GEMM_STAGE(1, 32);
  for (int t = 0; t < NT - 2; ++t) {
    GEMM_STAGE((t + 2) % 3, (t + 2) * 32);
    GEMM_STEP((t % 3), 8);
  }
  GEMM_STEP(((NT - 2) % 3), 4);
  GEMM_STEP(((NT - 1) % 3), 0);
#undef GEMM_STAGE
#undef GEMM_STEP

#pragma unroll
  for (int m = 0; m < 4; ++m) {
#pragma unroll
    for (int n = 0; n < 4; ++n) {
      int col = col0 + wc * 64 + n * 16 + lr;
      int r0 = row0 + wr * 64 + m * 16 + lg * 4;
      float bv = bias[col];
#pragma unroll
      for (int j = 0; j < 4; ++j)
        C[(size_t)(r0 + j) * DIM + col] = acc[m][n][j] + bv;
    }
  }
}

// ---------- flash attention v4 ----------
// grid (SEQ/128, NH, BB) = 512 blocks; block 512 = 8 waves, wave owns 16 q-rows.
// Double-buffered K/V staging; one __syncthreads per tile.
// Q pre-scaled by log2e/sqrt(SEQ) in projection; p = exp2(s) via v_exp_f32.

__global__ __launch_bounds__(512) void attn_kernel(const unsigned short* __restrict__ qb,
                                                   const unsigned short* __restrict__ kb,
                                                   const unsigned short* __restrict__ vT,
                                                   unsigned short* __restrict__ ctx) {
  __shared__ unsigned short lK[2][64 * 64];     // [key][d], XOR chunk-swizzled
  __shared__ unsigned short lV[2][64 * 64];     // [dv][key], XOR chunk-swizzled
  __shared__ unsigned short Pl[8][16 * 72];     // per-wave P [q][key], stride 72

  const int b = blockIdx.z, h = blockIdx.y;
  const int tid = threadIdx.x, lane = tid & 63, wave = tid >> 6;
  const int lr = lane & 15, lg = lane >> 4;
  const int q0 = blockIdx.x * 128 + wave * 16;

  // staging chunk mapping: 512 chunks per matrix, 1 K + 1 V chunk per thread
  const int sr = tid >> 3, sc = (tid & 7) ^ (sr & 7);
  const unsigned short* Kbase = kb + ((size_t)b * SEQ) * DIM + (size_t)h * HD;
  const unsigned short* Vbase = vT + (size_t)(b * NH + h) * HD * SEQ;

  // hoist Q fragments: rows q0+lr, d = c*32 + lg*8..+8
  bf16x8 qf0, qf1;
  {
    const unsigned short* qrow = qb + ((size_t)(b * SEQ) + q0 + lr) * DIM + h * HD;
    qf0 = *reinterpret_cast<const bf16x8*>(qrow + lg * 8);
    qf1 = *reinterpret_cast<const bf16x8*>(qrow + 32 + lg * 8);
  }

  float l_r[4] = {0.f, 0.f, 0.f, 0.f};
  f32x4 o_acc[4];
#pragma unroll
  for (int n = 0; n < 4; ++n) o_acc[n] = f32x4{0.f, 0.f, 0.f, 0.f};

  unsigned short* pw = Pl[wave];

  // prologue: stage tile 0 into buffer 0
  gload_lds16(Kbase + (size_t)sr * DIM + sc * 8, &lK[0][(wave * 64) * 8]);
  gload_lds16(Vbase + (size_t)sr * SEQ + sc * 8, &lV[0][(wave * 64) * 8]);
  __syncthreads();

  for (int t = 0; t < SEQ / 64; ++t) {
    const int cur = t & 1;
    if (t + 1 < SEQ / 64) {  // prefetch next tile into the other buffer
      const int nk = (t + 1) * 64;
      gload_lds16(Kbase + (size_t)(nk + sr) * DIM + sc * 8, &lK[cur ^ 1][(wave * 64) * 8]);
      gload_lds16(Vbase + (size_t)sr * SEQ + nk + sc * 8, &lV[cur ^ 1][(wave * 64) * 8]);
    }

    // QK^T: st[kt], q = q0+lg*4+j, key = kt*16+lr
    f32x4 st[4];
    __builtin_amdgcn_s_setprio(1);
#pragma unroll
    for (int kt = 0; kt < 4; ++kt) {
      const int row = kt * 16 + lr;
      const char* rbase = (const char*)&lK[cur][0] + row * 128;
      const int sw = (row & 7) << 4;
      bf16x8 kf0 = *reinterpret_cast<const bf16x8*>(rbase + ((lg * 16) ^ sw));
      bf16x8 kf1 = *reinterpret_cast<const bf16x8*>(rbase + ((64 + lg * 16) ^ sw));
      f32x4 a = {};
      a = __builtin_amdgcn_mfma_f32_16x16x32_bf16(qf0, kf0, a, 0, 0, 0);
      a = __builtin_amdgcn_mfma_f32_16x16x32_bf16(qf1, kf1, a, 0, 0, 0);
      st[kt] = a;
    }
    __builtin_amdgcn_s_setprio(0);

    // softmax numerator: p = 2^s (scale·log2e folded into Q projection)
#pragma unroll
    for (int j = 0; j < 4; ++j) {
      float p0 = fexp2(st[0][j]);
      float p1 = fexp2(st[1][j]);
      float p2 = fexp2(st[2][j]);
      float p3 = fexp2(st[3][j]);
      l_r[j] += (p0 + p1) + (p2 + p3);
      const int qrow = (lg * 4 + j) * 72;
      pw[qrow + lr] = f2bf(p0);
      pw[qrow + 16 + lr] = f2bf(p1);
      pw[qrow + 32 + lr] = f2bf(p2);
      pw[qrow + 48 + lr] = f2bf(p3);
    }

    // PV: o_acc[n] += P[q][k] V[k][dv]
#pragma unroll
    for (int c = 0; c < 2; ++c) {
      bf16x8 pf = *reinterpret_cast<const bf16x8*>((const char*)pw + lr * 144 + c * 64 + lg * 16);
      __builtin_amdgcn_s_setprio(1);
#pragma unroll
      for (int n = 0; n < 4; ++n) {
        const int row = n * 16 + lr;
        bf16x8 vf = *reinterpret_cast<const bf16x8*>(
            (const char*)&lV[cur][0] + row * 128 + ((c * 64 + lg * 16) ^ ((row & 7) << 4)));
        o_acc[n] = __builtin_amdgcn_mfma_f32_16x16x32_bf16(pf, vf, o_acc[n], 0, 0, 0);
      }
      __builtin_amdgcn_s_setprio(0);
    }

    __syncthreads();  // drains prefetch vmcnt + guards buffer reuse
  }

  // final l reduction + normalize, bounce through pw for coalesced stores
  float invl[4];
#pragma unroll
  for (int j = 0; j < 4; ++j) {
    float l = l_r[j];
#pragma unroll
    for (int msk = 1; msk < 16; msk <<= 1) l += __shfl_xor(l, msk);
    invl[j] = 1.f / l;
  }
#pragma unroll
  for (int n = 0; n < 4; ++n)
#pragma unroll
    for (int j = 0; j < 4; ++j)
      pw[(lg * 4 + j) * 72 + n * 16 + lr] = f2bf(o_acc[n][j] * invl[j]);

  // 16 rows x 8 chunks = 128 chunks per wave; 2 iters x 64 lanes.
#pragma unroll
  for (int it = 0; it < 2; ++it) {
    int idx = it * 64 + lane;
    int r = idx >> 3, cc = idx & 7;
    bf16x8 v = *reinterpret_cast<const bf16x8*>((const char*)pw + r * 144 + cc * 16);
    *reinterpret_cast<bf16x8*>(ctx + ((size_t)(b * SEQ) + q0 + r) * DIM + h * HD + cc * 8) = v;
  }
}

// ---------- launch ----------

extern "C" void kernel_launch(void* const* d_in, const int* in_sizes, int n_in,
                              void* d_out, int out_size, void* d_ws, size_t ws_size,
                              hipStream_t stream) {
  const float* query = (const float*)d_in[0];
  const float* key_  = (const float*)d_in[1];
  const float* value = (const float*)d_in[2];
  const float* Wq = (const float*)d_in[3];
  const float* bq = (const float*)d_in[4];
  const float* Wk = (const float*)d_in[5];
  const float* bk = (const float*)d_in[6];
  const float* Wv = (const float*)d_in[7];
  const float* bv = (const float*)d_in[8];
  const float* Wo = (const float*)d_in[9];
  const float* bo = (const float*)d_in[10];
  float* out = (float*)d_out;

  unsigned short* ws = (unsigned short*)d_ws;
  const size_t NM = (size_t)M * DIM;    // 4194304 elems
  const size_t NW = (size_t)DIM * DIM;  // 262144 elems
  unsigned short* xq   = ws;
  unsigned short* xk   = xq + NM;
  unsigned short* xv   = xk + NM;
  unsigned short* qb   = xv + NM;
  unsigned short* kbuf = qb + NM;
  unsigned short* vTb  = kbuf + NM;
  unsigned short* ctx  = vTb + NM;
  unsigned short* Wqt  = ctx + NM;
  unsigned short* Wkt  = Wqt + NW;
  unsigned short* Wvt  = Wkt + NW;
  unsigned short* Wot  = Wvt + NW;

  // converts
  cvt3_kernel<<<dim3((int)(NM / 1024), 3), 256, 0, stream>>>(query, key_, value, xq, xk, xv);
  cvt_t4_kernel<<<dim3(16, 16, 4), 256, 0, stream>>>(Wq, Wk, Wv, Wo, Wqt, Wkt, Wvt, Wot);

  // fused projections (counted-vmcnt pipeline; V written transposed in epilogue).
  // Q pre-scaled by log2e/sqrt(SEQ) for exp2-softmax.
  const float qscale = 0.03125f * 1.4426950408889634f;
  gemm_proj<<<dim3(M / 128, DIM / 128, 3), 256, 0, stream>>>(
      xq, xk, xv, Wqt, Wkt, Wvt, bq, bk, bv, qb, kbuf, vTb, qscale);

  // attention
  attn_kernel<<<dim3(SEQ / 128, NH, BB), 512, 0, stream>>>(qb, kbuf, vTb, ctx);

  // output projection (fp32 out + bias)
  gemm_out<<<dim3(M / 128, DIM / 128), 256, 0, stream>>>(ctx, Wot, bo, out);
}